// Round 4
// baseline (2563.348 us; speedup 1.0000x reference)
//
#include <hip/hip_runtime.h>

// (B, L, C, H, O) = (4096, 256, 16, 128, 4)
#define NB 4096
#define NL 256
#define NC 16
#define NH 128
#define NO 4

// readlane -> SGPR (lane index is a compile-time literal everywhere we use it)
__device__ __forceinline__ float rl(float v, int l) {
  return __uint_as_float(__builtin_amdgcn_readlane(__float_as_uint(v), l));
}

__device__ __forceinline__ float fast_exp2(float x) {
  return __builtin_amdgcn_exp2f(x);
}
__device__ __forceinline__ float fast_rcp(float x) {
  return __builtin_amdgcn_rcpf(x);
}

// DPP add step: x += dpp_shifted(x), OOB lanes contribute 0 (bound_ctrl=true).
// Template params so the builtin sees integer-constant-expressions.
template <int CTRL, int RMASK, int BMASK>
__device__ __forceinline__ float dppadd(float x) {
  int t = __builtin_amdgcn_update_dpp(0, __float_as_int(x), CTRL, RMASK, BMASK, true);
  return x + __int_as_float(t);
}
// Canonical GCN full-wave sum: result valid in lane 63. Zero DS traffic.
__device__ __forceinline__ float sum64_l63(float x) {
  x = dppadd<0x111, 0xF, 0xF>(x);  // row_shr:1
  x = dppadd<0x112, 0xF, 0xF>(x);  // row_shr:2
  x = dppadd<0x114, 0xF, 0xE>(x);  // row_shr:4
  x = dppadd<0x118, 0xF, 0xC>(x);  // row_shr:8
  x = dppadd<0x142, 0xA, 0xF>(x);  // row_bcast:15
  x = dppadd<0x143, 0xC, 0xF>(x);  // row_bcast:31
  return x;
}
// Row-of-16 sum: lane 15 holds sum of lanes 0..15.
__device__ __forceinline__ float sum16_l15(float x) {
  x = dppadd<0x111, 0xF, 0xF>(x);
  x = dppadd<0x112, 0xF, 0xF>(x);
  x = dppadd<0x114, 0xF, 0xE>(x);
  x = dppadd<0x118, 0xF, 0xC>(x);
  return x;
}

#define REP16(M) M(0) M(1) M(2) M(3) M(4) M(5) M(6) M(7) \
                 M(8) M(9) M(10) M(11) M(12) M(13) M(14) M(15)

// 96 individually-named weight scalars: cannot be demoted to scratch.
// Pre-scaled by 2*log2(e) so tanh(x) = 1 - 2/exp2(s*x) chain needs no extra mul.
#define DECLW(i)                                                               \
  const float w2aA##i = W2[hA * NC + i] * SC;                                  \
  const float w2bA##i = W2[NH * NC + hA * NC + i] * SC;                        \
  const float b2A##i  = b2[hA * NC + i] * SC;                                  \
  const float w2aB##i = W2[hB * NC + i] * SC;                                  \
  const float w2bB##i = W2[NH * NC + hB * NC + i] * SC;                        \
  const float b2B##i  = b2[hB * NC + i] * SC;

// One (c) slice of the tanh/einsum: 8 VALU + 4 trans.  hh0/hh1/xc are SGPRs.
#define ENT(i)                                                                 \
  {                                                                            \
    float xc = rl(xdv_, i);                                                    \
    float eA = fast_exp2(fmaf(w2aA##i, hh0, fmaf(w2bA##i, hh1, b2A##i)));      \
    float eB = fast_exp2(fmaf(w2aB##i, hh0, fmaf(w2bB##i, hh1, b2B##i)));      \
    accA = fmaf(xc, fast_rcp(eA + 1.0f), accA);                                \
    accB = fmaf(xc, fast_rcp(eB + 1.0f), accB);                                \
  }

// vf(z, xdot): h = relu(z@W1+b1); k = SX - 2*sum_c xc/(exp2(arg)+1)
#define VF(ZSA, ZSB, XDV, SXS, K0, K1)                                         \
  {                                                                            \
    float xdv_ = (XDV);                                                        \
    float p0v = fmaf((ZSA), w1A0, (ZSB) * w1B0);                               \
    float p1v = fmaf((ZSA), w1A1, (ZSB) * w1B1);                               \
    p0v = sum64_l63(p0v);                                                      \
    p1v = sum64_l63(p1v);                                                      \
    float hh0v = fmaxf(p0v + b1_0, 0.0f);                                      \
    float hh1v = fmaxf(p1v + b1_1, 0.0f);                                      \
    float hh0 = rl(hh0v, 63);                                                  \
    float hh1 = rl(hh1v, 63);                                                  \
    float accA = 0.0f, accB = 0.0f;                                            \
    REP16(ENT)                                                                 \
    (K0) = fmaf(-2.0f, accA, (SXS));                                           \
    (K1) = fmaf(-2.0f, accB, (SXS));                                           \
  }

// out[b,t,:] = z @ W_out + b_out — DPP-reduce, lane 63 stores directly.
#define STORE_OUT(T, ZA_, ZB_)                                                 \
  {                                                                            \
    float q0 = fmaf((ZA_), woA0, (ZB_) * woB0);                                \
    float q1 = fmaf((ZA_), woA1, (ZB_) * woB1);                                \
    float q2 = fmaf((ZA_), woA2, (ZB_) * woB2);                                \
    float q3 = fmaf((ZA_), woA3, (ZB_) * woB3);                                \
    q0 = sum64_l63(q0);                                                        \
    q1 = sum64_l63(q1);                                                        \
    q2 = sum64_l63(q2);                                                        \
    q3 = sum64_l63(q3);                                                        \
    if (lane == 63) {                                                          \
      float4 r_;                                                               \
      r_.x = q0 + bo0; r_.y = q1 + bo1; r_.z = q2 + bo2; r_.w = q3 + bo3;      \
      *(float4*)(obase + (size_t)(T)*NO) = r_;                                 \
    }                                                                          \
  }

#define Z0E(i)                                                                 \
  {                                                                            \
    float xc = rl(v0, i);                                                      \
    za = fmaf(xc, W_init[i * NH + hA], za);                                    \
    zb = fmaf(xc, W_init[i * NH + hB], zb);                                    \
  }

__global__ __launch_bounds__(256, 2) void ncde_kernel(
    const float* __restrict__ coeffs,  // (B, L-1, 4*C)
    const float* __restrict__ W_init,  // (C, H)
    const float* __restrict__ b_init,  // (H,)
    const float* __restrict__ W1,      // (H, 2)
    const float* __restrict__ b1,      // (2,)
    const float* __restrict__ W2,      // (2, H*C)
    const float* __restrict__ b2,      // (H*C,)
    const float* __restrict__ W_out,   // (H, O)
    const float* __restrict__ b_out,   // (O,)
    float* __restrict__ out)           // (B, L, O)
{
  const int lane = threadIdx.x & 63;
  const int wid  = threadIdx.x >> 6;
  const int bat  = blockIdx.x * 4 + wid;  // one wave per batch element
  const int hA = lane;
  const int hB = lane + 64;
  const float SC = 2.885390081777927f;  // 2*log2(e)

  REP16(DECLW)

  const float w1A0 = W1[hA * 2 + 0], w1A1 = W1[hA * 2 + 1];
  const float w1B0 = W1[hB * 2 + 0], w1B1 = W1[hB * 2 + 1];
  const float woA0 = W_out[hA * NO + 0], woA1 = W_out[hA * NO + 1];
  const float woA2 = W_out[hA * NO + 2], woA3 = W_out[hA * NO + 3];
  const float woB0 = W_out[hB * NO + 0], woB1 = W_out[hB * NO + 1];
  const float woB2 = W_out[hB * NO + 2], woB3 = W_out[hB * NO + 3];
  const float bo0 = b_out[0], bo1 = b_out[1], bo2 = b_out[2], bo3 = b_out[3];
  const float b1_0 = b1[0], b1_1 = b1[1];

  const float* crow = coeffs + (size_t)bat * (NL - 1) * (4 * NC);
  float* obase = out + (size_t)bat * NL * NO;

  // ---- z0 = X0 @ W_init + b_init ----
  float v0 = crow[lane];
  float za = b_init[hA], zb = b_init[hB];
  REP16(Z0E)

  STORE_OUT(0, za, zb);

  // bpermute byte addresses for gathering sb/sc/sd segments (loop-invariant)
  const int cl = lane & 15;
  const int ab = (16 + cl) << 2, ac = (32 + cl) << 2, ad = (48 + cl) << 2;

#pragma unroll 1
  for (int s = 0; s < NL - 1; ++s) {
    float vrow = crow[s * 64 + lane];
    int vri = __float_as_int(vrow);
    float vb = __int_as_float(__builtin_amdgcn_ds_bpermute(ab, vri));
    float vc = __int_as_float(__builtin_amdgcn_ds_bpermute(ac, vri));
    float vd = __int_as_float(__builtin_amdgcn_ds_bpermute(ad, vri));

    float xd0 = vb;
    float xdh = fmaf(0.25f, vd, fmaf(0.5f, vc, vb));
    float xd1 = vb + (vc + vd);

    // SX = sum_c xdot_c  (wave-uniform -> SGPR)
    float sx0 = rl(sum16_l15(xd0), 15);
    float sxh = rl(sum16_l15(xdh), 15);
    float sx1 = rl(sum16_l15(xd1), 15);

    float k10, k11, k20, k21, k30, k31, k40, k41;
    VF(za, zb, xd0, sx0, k10, k11);
    VF(fmaf(0.5f, k10, za), fmaf(0.5f, k11, zb), xdh, sxh, k20, k21);
    VF(fmaf(0.5f, k20, za), fmaf(0.5f, k21, zb), xdh, sxh, k30, k31);
    VF(za + k30, zb + k31, xd1, sx1, k40, k41);

    za += ((k10 + k40) + 2.0f * (k20 + k30)) * (1.0f / 6.0f);
    zb += ((k11 + k41) + 2.0f * (k21 + k31)) * (1.0f / 6.0f);

    STORE_OUT(s + 1, za, zb);
  }
}

extern "C" void kernel_launch(void* const* d_in, const int* in_sizes, int n_in,
                              void* d_out, int out_size, void* d_ws, size_t ws_size,
                              hipStream_t stream) {
  const float* coeffs = (const float*)d_in[0];
  const float* W_init = (const float*)d_in[1];
  const float* b_init = (const float*)d_in[2];
  const float* W1     = (const float*)d_in[3];
  const float* b1     = (const float*)d_in[4];
  const float* W2     = (const float*)d_in[5];
  const float* b2     = (const float*)d_in[6];
  const float* W_out  = (const float*)d_in[7];
  const float* b_out  = (const float*)d_in[8];
  float* out = (float*)d_out;

  ncde_kernel<<<NB / 4, 256, 0, stream>>>(coeffs, W_init, b_init, W1, b1, W2,
                                          b2, W_out, b_out, out);
}